// Round 2
// baseline (113021.704 us; speedup 1.0000x reference)
//
#include <hip/hip_runtime.h>
#include <hip/hip_bf16.h>

#define S_LEN 32768
#define EMB   256
#define HID   512
#define G3H   1536   // 3*HID
#define NWG   8
#define NTHR  512
#define NOUT  8

// ws layout (float units):
// [0, 9216)        gx_table (6 x 1536)  : emb@W_ih.T + b_ih
// [9216, 10240)    hbuf double buffer 2 x 512
// [10240, 10752)   flags (int view), one per WG at stride 64 ints (256B apart)
#define WS_GX    0
#define WS_HBUF  9216
#define WS_FLAGS 10240

__global__ __launch_bounds__(256) void gru_precompute_kernel(
    const float* __restrict__ emb, const float* __restrict__ W_ih,
    const float* __restrict__ b_ih, float* __restrict__ ws)
{
    int idx = blockIdx.x * 256 + threadIdx.x;
    if (idx < 6 * G3H) {
        int v = idx / G3H, r = idx - v * G3H;
        const float* er = emb + v * EMB;
        const float* wr = W_ih + r * EMB;
        float s = 0.f;
        #pragma unroll 8
        for (int e = 0; e < EMB; ++e) s += er[e] * wr[e];
        ws[WS_GX + idx] = s + b_ih[r];
    }
    if (blockIdx.x == 0) {
        // zero h double-buffer and flags with agent-scope atomic stores so the
        // persistent kernel's coherent (cache-bypassing) reads see them.
        for (int j = threadIdx.x; j < 2 * HID; j += 256)
            __hip_atomic_store((int*)&ws[WS_HBUF + j], 0,
                               __ATOMIC_RELAXED, __HIP_MEMORY_SCOPE_AGENT);
        for (int j = threadIdx.x; j < 512; j += 256)
            __hip_atomic_store((int*)&ws[WS_FLAGS + j], 0,
                               __ATOMIC_RELAXED, __HIP_MEMORY_SCOPE_AGENT);
    }
}

// Persistent GRU kernel: 8 WGs x 512 threads. WG g owns h[g*64 .. g*64+64).
// Each wave (8 per WG) owns 8 h-indices; each 8-lane group owns one h-index;
// lane k of a group owns columns [k*64, k*64+64) of the 3 gate rows.
// Weights live in VGPRs: 3 gates x 16 float4 = 48 float4 = 192 VGPRs/lane.
__global__ __launch_bounds__(512) void gru_persistent_kernel(
    const int* __restrict__ seq, const float* __restrict__ W_hh,
    const float* __restrict__ b_hh, const float* __restrict__ W_out,
    const float* __restrict__ b_out, float* __restrict__ ws,
    float* __restrict__ out)
{
    __shared__ __align__(16) float h_lds[544];      // j -> j + 4*(j>>6) padding
    __shared__ float gx_lds[6 * 3 * 64];            // [v][gate][il], b_hh folded for r,z
    __shared__ float bhn_lds[64];                   // b_hh for n gate kept separate
    __shared__ unsigned char seq_lds[S_LEN];        // packed vocab ids

    const int g    = blockIdx.x;
    const int tid  = threadIdx.x;
    const int wid  = tid >> 6;
    const int lane = tid & 63;
    const int grp  = lane >> 3;
    const int k    = lane & 7;
    const int il   = wid * 8 + grp;   // local h index 0..63
    const int i    = g * 64 + il;     // global h index

    float* hbuf = ws + WS_HBUF;
    int*   flags = (int*)(ws + WS_FLAGS);

    // ---- one-time weight load into registers ----
    float4 WR[16], WZ[16], WN[16];
    {
        const float4* pr = (const float4*)(W_hh + (size_t)i * HID + k * 64);
        const float4* pz = (const float4*)(W_hh + (size_t)(HID + i) * HID + k * 64);
        const float4* pn = (const float4*)(W_hh + (size_t)(2 * HID + i) * HID + k * 64);
        #pragma unroll
        for (int c = 0; c < 16; ++c) { WR[c] = pr[c]; WZ[c] = pz[c]; WN[c] = pn[c]; }
    }

    // ---- one-time LDS staging ----
    for (int idx = tid; idx < 6 * 3 * 64; idx += NTHR) {
        int v = idx / 192, rem = idx - v * 192, gate = rem >> 6, ii = rem & 63;
        float val = ws[WS_GX + v * G3H + gate * HID + g * 64 + ii];
        if (gate < 2) val += b_hh[gate * HID + g * 64 + ii];  // fold b_hh for r,z only
        gx_lds[idx] = val;
    }
    if (tid < 64) bhn_lds[tid] = b_hh[2 * HID + g * 64 + tid];
    for (int p = tid; p < S_LEN; p += NTHR) seq_lds[p] = (unsigned char)seq[p];
    __syncthreads();

    const int myflag = wid * 64;

    for (int t = 0; t < S_LEN; ++t) {
        const int p = t & 1;
        // wait for the producer of slice `wid` of h_t, then stage own element
        while (__hip_atomic_load(&flags[myflag], __ATOMIC_ACQUIRE,
                                 __HIP_MEMORY_SCOPE_AGENT) < t) {}
        int hbits = __hip_atomic_load((int*)&hbuf[p * HID + tid],
                                      __ATOMIC_RELAXED, __HIP_MEMORY_SCOPE_AGENT);
        h_lds[tid + ((tid >> 6) << 2)] = __int_as_float(hbits);
        __syncthreads();

        // partial dots over this lane's 64 columns
        float ar = 0.f, az = 0.f, an = 0.f;
        const float4* hp = (const float4*)&h_lds[k * 68];
        #pragma unroll
        for (int c = 0; c < 16; ++c) {
            float4 hv = hp[c];
            ar += WR[c].x * hv.x; ar += WR[c].y * hv.y;
            ar += WR[c].z * hv.z; ar += WR[c].w * hv.w;
            az += WZ[c].x * hv.x; az += WZ[c].y * hv.y;
            az += WZ[c].z * hv.z; az += WZ[c].w * hv.w;
            an += WN[c].x * hv.x; an += WN[c].y * hv.y;
            an += WN[c].z * hv.z; an += WN[c].w * hv.w;
        }
        // reduce across the 8 lanes of the group
        #pragma unroll
        for (int m = 1; m < 8; m <<= 1) {
            ar += __shfl_xor(ar, m, 64);
            az += __shfl_xor(az, m, 64);
            an += __shfl_xor(an, m, 64);
        }

        // gates (all 8 lanes redundantly; lane k==0 stores)
        int v = seq_lds[t];
        float gxr = gx_lds[v * 192 + il];
        float gxz = gx_lds[v * 192 + 64 + il];
        float gxn = gx_lds[v * 192 + 128 + il];
        float r = 1.f / (1.f + expf(-(gxr + ar)));
        float z = 1.f / (1.f + expf(-(gxz + az)));
        float n = tanhf(gxn + r * (an + bhn_lds[il]));
        float hold = h_lds[g * 68 + il];
        float hn = (1.f - z) * n + z * hold;

        if (k == 0) {
            __hip_atomic_store((int*)&hbuf[(1 - p) * HID + i], __float_as_int(hn),
                               __ATOMIC_RELAXED, __HIP_MEMORY_SCOPE_AGENT);
        }
        __syncthreads();
        if (tid == 0) {
            __hip_atomic_store(&flags[g * 64], t + 1,
                               __ATOMIC_RELEASE, __HIP_MEMORY_SCOPE_AGENT);
        }
    }

    // ---- epilogue: WG 0 computes out = W_out @ h_T + b_out ----
    if (g == 0) {
        while (__hip_atomic_load(&flags[myflag], __ATOMIC_ACQUIRE,
                                 __HIP_MEMORY_SCOPE_AGENT) < S_LEN) {}
        // h_{S} lives in hbuf[S_LEN & 1] == hbuf[0]
        int hbits = __hip_atomic_load((int*)&hbuf[0 * HID + tid],
                                      __ATOMIC_RELAXED, __HIP_MEMORY_SCOPE_AGENT);
        h_lds[tid + ((tid >> 6) << 2)] = __int_as_float(hbits);
        __syncthreads();
        // wave w computes out[w] (NOUT == 8 == waves per WG)
        float s = 0.f;
        #pragma unroll
        for (int m = 0; m < 8; ++m) {
            int j = lane + 64 * m;
            s += W_out[wid * HID + j] * h_lds[lane + 68 * m];
        }
        #pragma unroll
        for (int m = 1; m < 64; m <<= 1) s += __shfl_xor(s, m, 64);
        if (lane == 0) out[wid] = s + b_out[wid];
    }
}

extern "C" void kernel_launch(void* const* d_in, const int* in_sizes, int n_in,
                              void* d_out, int out_size, void* d_ws, size_t ws_size,
                              hipStream_t stream) {
    const int*   seq   = (const int*)d_in[0];
    const float* emb   = (const float*)d_in[1];
    const float* W_ih  = (const float*)d_in[2];
    const float* W_hh  = (const float*)d_in[3];
    const float* b_ih  = (const float*)d_in[4];
    const float* b_hh  = (const float*)d_in[5];
    const float* W_out = (const float*)d_in[6];
    const float* b_out = (const float*)d_in[7];
    float* ws = (float*)d_ws;
    float* out = (float*)d_out;

    gru_precompute_kernel<<<36, 256, 0, stream>>>(emb, W_ih, b_ih, ws);
    gru_persistent_kernel<<<NWG, NTHR, 0, stream>>>(seq, W_hh, b_hh, W_out, b_out,
                                                    ws, out);
}

// Round 3
// 59818.884 us; speedup vs baseline: 1.8894x; 1.8894x over previous
//
#include <hip/hip_runtime.h>

#define S_LEN 32768
#define EMB   256
#define HID   512
#define G3H   1536   // 3*HID
#define NWG   8
#define NTHR  512
#define NOUT  8

// ws layout (float units):
// [0, 9216)        gx_table (6 x 1536)  : emb@W_ih.T + b_ih
// [9216, 11264)    hbuf: 2 x 512 tagged u64 words (8KB). word = (tag<<32)|f32bits
#define WS_GX    0
#define WS_HBUF  9216

__global__ __launch_bounds__(256) void gru_precompute_kernel(
    const float* __restrict__ emb, const float* __restrict__ W_ih,
    const float* __restrict__ b_ih, float* __restrict__ ws)
{
    int idx = blockIdx.x * 256 + threadIdx.x;
    if (idx < 6 * G3H) {
        int v = idx / G3H, r = idx - v * G3H;
        const float* er = emb + v * EMB;
        const float* wr = W_ih + r * EMB;
        float s = 0.f;
        #pragma unroll 8
        for (int e = 0; e < EMB; ++e) s += er[e] * wr[e];
        ws[WS_GX + idx] = s + b_ih[r];
    }
    if (blockIdx.x == 0) {
        // zero the tagged h buffer (tag 0 == h_0 == 0) with agent-scope stores
        // so the persistent kernel's cache-bypassing polls see them.
        for (int j = threadIdx.x; j < 2048; j += 256)
            __hip_atomic_store((int*)&ws[WS_HBUF + j], 0,
                               __ATOMIC_RELAXED, __HIP_MEMORY_SCOPE_AGENT);
    }
}

// Persistent GRU kernel: 8 WGs x 512 threads. WG g owns h[g*64 .. g*64+64).
// Wave wid owns h indices g*64 + wid*8 + (0..7); each 8-lane group owns one
// h index; lane k of a group owns columns [k*64, (k+1)*64) of the 3 gate rows.
// Weights in VGPRs: 3 gates x 16 float4 = 192 VGPRs/lane -> needs the 256 cap
// from __launch_bounds__(512, 2) (2 waves/SIMD = exactly one 8-wave block).
__global__ __launch_bounds__(512, 2) void gru_persistent_kernel(
    const int* __restrict__ seq, const float* __restrict__ W_hh,
    const float* __restrict__ b_hh, const float* __restrict__ W_out,
    const float* __restrict__ b_out, float* __restrict__ ws,
    float* __restrict__ out)
{
    __shared__ __align__(16) float h_lds[2][544];   // j -> j + 4*(j>>6) padding
    __shared__ float gx_lds[6 * 3 * 64];            // [v][gate][il], b_hh folded for r,z
    __shared__ float bhn_lds[64];                   // b_hh for n gate kept separate
    __shared__ unsigned char seq_lds[S_LEN];        // packed vocab ids

    const int g    = blockIdx.x;
    const int tid  = threadIdx.x;
    const int wid  = tid >> 6;
    const int lane = tid & 63;
    const int grp  = lane >> 3;
    const int k    = lane & 7;
    const int il   = wid * 8 + grp;   // local h index 0..63
    const int i    = g * 64 + il;     // global h index

    unsigned long long* hbuf = (unsigned long long*)(ws + WS_HBUF);

    // ---- one-time weight load into registers ----
    float4 WR[16], WZ[16], WN[16];
    {
        const float4* pr = (const float4*)(W_hh + (size_t)i * HID + k * 64);
        const float4* pz = (const float4*)(W_hh + (size_t)(HID + i) * HID + k * 64);
        const float4* pn = (const float4*)(W_hh + (size_t)(2 * HID + i) * HID + k * 64);
        #pragma unroll
        for (int c = 0; c < 16; ++c) { WR[c] = pr[c]; WZ[c] = pz[c]; WN[c] = pn[c]; }
    }

    // ---- one-time LDS staging ----
    for (int idx = tid; idx < 6 * 3 * 64; idx += NTHR) {
        int v = idx / 192, rem = idx - v * 192, gate = rem >> 6, ii = rem & 63;
        float val = ws[WS_GX + v * G3H + gate * HID + g * 64 + ii];
        if (gate < 2) val += b_hh[gate * HID + g * 64 + ii];  // fold b_hh for r,z only
        gx_lds[idx] = val;
    }
    if (tid < 64) bhn_lds[tid] = b_hh[2 * HID + g * 64 + tid];
    for (int p = tid; p < S_LEN; p += NTHR) seq_lds[p] = (unsigned char)seq[p];
    __syncthreads();

    for (int t = 0; t < S_LEN; ++t) {
        const int p = t & 1;
        // gate-x preactivations are h-independent: fetch before the poll
        int v = seq_lds[t];
        float gxr = gx_lds[v * 192 + il];
        float gxz = gx_lds[v * 192 + 64 + il];
        float gxn = gx_lds[v * 192 + 128 + il];

        // spin on own element's tagged word (single round trip: tag+data fused)
        unsigned long long w;
        do {
            w = __hip_atomic_load(&hbuf[p * HID + tid], __ATOMIC_RELAXED,
                                  __HIP_MEMORY_SCOPE_AGENT);
        } while ((unsigned)(w >> 32) != (unsigned)t);
        h_lds[p][tid + ((tid >> 6) << 2)] = __uint_as_float((unsigned)w);
        __syncthreads();   // sole barrier per step (h_lds parity double buffer)

        // partial dots over this lane's 64 columns (columns k*64.. = slice k)
        float ar = 0.f, az = 0.f, an = 0.f;
        const float4* hp = (const float4*)&h_lds[p][k * 68];
        #pragma unroll
        for (int c = 0; c < 16; ++c) {
            float4 hv = hp[c];
            ar += WR[c].x * hv.x; ar += WR[c].y * hv.y;
            ar += WR[c].z * hv.z; ar += WR[c].w * hv.w;
            az += WZ[c].x * hv.x; az += WZ[c].y * hv.y;
            az += WZ[c].z * hv.z; az += WZ[c].w * hv.w;
            an += WN[c].x * hv.x; an += WN[c].y * hv.y;
            an += WN[c].z * hv.z; an += WN[c].w * hv.w;
        }
        // reduce across the 8 lanes of the group
        #pragma unroll
        for (int m = 1; m < 8; m <<= 1) {
            ar += __shfl_xor(ar, m, 64);
            az += __shfl_xor(az, m, 64);
            an += __shfl_xor(an, m, 64);
        }

        // gates (all 8 lanes redundantly; lane k==0 stores)
        float r = __fdividef(1.f, 1.f + __expf(-(gxr + ar)));
        float z = __fdividef(1.f, 1.f + __expf(-(gxz + az)));
        float nx = gxn + r * (an + bhn_lds[il]);
        float n = 1.f - __fdividef(2.f, 1.f + __expf(2.f * nx));  // tanh(nx)
        float hold = h_lds[p][g * 68 + il];
        float hn = (1.f - z) * n + z * hold;

        if (k == 0) {
            unsigned long long wout =
                ((unsigned long long)(unsigned)(t + 1) << 32) |
                (unsigned long long)__float_as_uint(hn);
            __hip_atomic_store(&hbuf[(1 - p) * HID + i], wout,
                               __ATOMIC_RELAXED, __HIP_MEMORY_SCOPE_AGENT);
        }
        // no trailing barrier: next step stages into h_lds[1-p]
    }

    // ---- epilogue: WG 0 computes out = W_out @ h_T + b_out ----
    if (g == 0) {
        // h_{S_LEN} lives in buffer parity S_LEN&1 == 0 with tag S_LEN
        unsigned long long w;
        do {
            w = __hip_atomic_load(&hbuf[0 * HID + tid], __ATOMIC_RELAXED,
                                  __HIP_MEMORY_SCOPE_AGENT);
        } while ((unsigned)(w >> 32) != (unsigned)S_LEN);
        h_lds[0][tid + ((tid >> 6) << 2)] = __uint_as_float((unsigned)w);
        __syncthreads();
        // wave w computes out[w] (NOUT == 8 == waves per WG)
        float s = 0.f;
        #pragma unroll
        for (int m = 0; m < 8; ++m) {
            int j = lane + 64 * m;
            s += W_out[wid * HID + j] * h_lds[0][lane + 68 * m];
        }
        #pragma unroll
        for (int m = 1; m < 64; m <<= 1) s += __shfl_xor(s, m, 64);
        if (lane == 0) out[wid] = s + b_out[wid];
    }
}

extern "C" void kernel_launch(void* const* d_in, const int* in_sizes, int n_in,
                              void* d_out, int out_size, void* d_ws, size_t ws_size,
                              hipStream_t stream) {
    const int*   seq   = (const int*)d_in[0];
    const float* emb   = (const float*)d_in[1];
    const float* W_ih  = (const float*)d_in[2];
    const float* W_hh  = (const float*)d_in[3];
    const float* b_ih  = (const float*)d_in[4];
    const float* b_hh  = (const float*)d_in[5];
    const float* W_out = (const float*)d_in[6];
    const float* b_out = (const float*)d_in[7];
    float* ws = (float*)d_ws;
    float* out = (float*)d_out;

    gru_precompute_kernel<<<36, 256, 0, stream>>>(emb, W_ih, b_ih, ws);
    gru_persistent_kernel<<<NWG, NTHR, 0, stream>>>(seq, W_hh, b_hh, W_out, b_out,
                                                    ws, out);
}